// Round 3
// baseline (163.740 us; speedup 1.0000x reference)
//
#include <hip/hip_runtime.h>

#define SDIM 256
#define NSEQ 256
#define CDIM 32
#define CZ 128
#define IB 8
#define JB 4

typedef __bf16 bfx8 __attribute__((ext_vector_type(8)));
typedef float fx4 __attribute__((ext_vector_type(4)));
typedef float f32x16 __attribute__((ext_vector_type(16)));
typedef unsigned int u32x2 __attribute__((ext_vector_type(2)));

__device__ __forceinline__ unsigned short f2bf(float f) {
  unsigned int u = __float_as_uint(f);
  u += 0x7fffu + ((u >> 16) & 1u);   // round-to-nearest-even
  return (unsigned short)(u >> 16);
}

__device__ __forceinline__ unsigned int cvtpk(float lo, float hi) {
  unsigned int r;
  asm("v_cvt_pk_bf16_f32 %0, %1, %2" : "=v"(r) : "v"(lo), "v"(hi));
  return r;
}

// O element (d,c) lives at k' = sigma(d,c); W2 is repacked to match.
// sigma: k'[0:2]=c[0:2], k'[3]=d[0], k'[4]=c[3], k'[5:7]=d[1:3], k'[8]=c[4], k'[9]=d[4]
// (chosen so O-writes spread over 16 LDS 8B-slots and O-reads are quad-minimal)

// ---------------- prep: LN + ab projection (-> bf16, transposed) + W_out -> w2T (frag-coalesced) ----------------
__global__ __launch_bounds__(256) void opm_prep(
    const float* __restrict__ m_si, const float* __restrict__ gamma, const float* __restrict__ beta,
    const float* __restrict__ Wab, const float* __restrict__ Wout,
    unsigned short* __restrict__ a_t, unsigned short* __restrict__ b_t,
    unsigned short* __restrict__ w2T)
{
  const int b = blockIdx.x;
  const int t = threadIdx.x;
  if (b < SDIM) {
    __shared__ float wab[2 * CDIM * CDIM];   // 64x32
    __shared__ float gbuf[2 * CDIM];
    for (int k = t; k < 2 * CDIM * CDIM; k += 256) wab[k] = Wab[k];
    if (t < CDIM) { gbuf[t] = gamma[t]; gbuf[CDIM + t] = beta[t]; }
    __syncthreads();

    float x[CDIM];
    const float* src = m_si + (b * NSEQ + t) * CDIM;
#pragma unroll
    for (int c4 = 0; c4 < CDIM / 4; ++c4) {
      fx4 v = *(const fx4*)(src + c4 * 4);
      x[c4 * 4 + 0] = v[0]; x[c4 * 4 + 1] = v[1];
      x[c4 * 4 + 2] = v[2]; x[c4 * 4 + 3] = v[3];
    }
    float mu = 0.f;
#pragma unroll
    for (int c = 0; c < CDIM; ++c) mu += x[c];
    mu *= (1.f / CDIM);
    float var = 0.f;
#pragma unroll
    for (int c = 0; c < CDIM; ++c) { float d = x[c] - mu; var += d * d; }
    var *= (1.f / CDIM);
    const float inv = rsqrtf(var + 1e-5f);
#pragma unroll
    for (int c = 0; c < CDIM; ++c) x[c] = (x[c] - mu) * inv * gbuf[c] + gbuf[CDIM + c];

    for (int dp = 0; dp < 2 * CDIM; ++dp) {
      float s = 0.f;
#pragma unroll
      for (int c = 0; c < CDIM; ++c) s += x[c] * wab[dp * CDIM + c];
      const unsigned short hv = f2bf(s);
      if (dp < CDIM) a_t[(b * CDIM + dp) * NSEQ + t] = hv;
      else           b_t[(b * CDIM + (dp - CDIM)) * NSEQ + t] = hv;
    }
  } else {
    // w2T[dest]: dest bits: idx[0:2], zl[3:7], h[8], ks[9:14], zq[15:16]
    // holds Wout[z' = zq*32+zl][orig k = c*32 + d] with (d,c) = sigma^-1(ks*16+h*8+idx)
    const int idx0 = (b - SDIM) * 256 + t;   // 0..2047
    const int base = idx0 * 64;
#pragma unroll 8
    for (int u = 0; u < 64; ++u) {
      const int dest = base + u;
      const int idx = dest & 7;
      const int zl  = (dest >> 3) & 31;
      const int h   = (dest >> 8) & 1;
      const int ks  = (dest >> 9) & 63;
      const int zq  = dest >> 15;
      const int kp  = ks * 16 + h * 8 + idx;
      const int c = (kp & 7) | (((kp >> 4) & 1) << 3) | (((kp >> 8) & 1) << 4);
      const int d = ((kp >> 3) & 1) | (((kp >> 5) & 7) << 1) | (((kp >> 9) & 1) << 4);
      const int z = zq * 32 + zl;
      w2T[dest] = f2bf(Wout[z * 1024 + c * CDIM + d]);
    }
  }
}

// ---------------- main: per-block 8x4 (i,j) pairs ----------------
// phase A (no LDS, no barriers): acc[4][4] per wave via direct global->VGPR fragment loads
// phase B: Z = W2T(128x1024) . O(1024x32) via 32x32x16 MFMA, 4 z-tiles x 2 K-halves, LDS reduction
__global__ __launch_bounds__(512, 4) void opm_main(
    const unsigned short* __restrict__ a_t, const unsigned short* __restrict__ b_t,
    const unsigned short* __restrict__ w2T, const float* __restrict__ bout,
    float* __restrict__ out)
{
  __shared__ __align__(16) char o_sh[65536];

  const int tid = threadIdx.x;
  const int lane = tid & 63;
  const int wid = tid >> 6;           // 0..7
  const int g = lane >> 4;            // 0..3
  const int l15 = lane & 15;

  // XCD swizzle (bijective: 2048 % 8 == 0): each XCD owns 4 consecutive i-rows -> a panels + W2 L2-hot
  const int bxr = blockIdx.x;
  const int bx = (bxr & 7) * 256 + (bxr >> 3);
  const int i0 = (bx >> 6) * IB;      // 32 i-tiles
  const int j0 = (bx & 63) * JB;      // 64 j-tiles

  // ---- phase A: 4 row-groups (mq) x 2 col-groups (nq)
  const int mq = wid >> 1;            // 0..3  (64 rows each)
  const int nq = wid & 1;             // 0..1  (64 cols each)

  const unsigned short* aP = a_t + (i0 * 32 + mq * 64 + l15) * 256 + g * 8;
  const unsigned short* bP = b_t + (j0 * 32 + nq * 64 + l15) * 256 + g * 8;

  fx4 acc[4][4] = {};
#pragma unroll
  for (int nc = 0; nc < 8; ++nc) {
    bfx8 af[4], bf[4];
#pragma unroll
    for (int mi = 0; mi < 4; ++mi) af[mi] = *(const bfx8*)(aP + mi * 4096 + nc * 32);
#pragma unroll
    for (int ni = 0; ni < 4; ++ni) bf[ni] = *(const bfx8*)(bP + ni * 4096 + nc * 32);
#pragma unroll
    for (int mi = 0; mi < 4; ++mi)
#pragma unroll
      for (int ni = 0; ni < 4; ++ni)
        acc[mi][ni] = __builtin_amdgcn_mfma_f32_16x16x32_bf16(af[mi], bf[ni], acc[mi][ni], 0, 0, 0);
  }

  // ---- O -> LDS (bf16), layout byte = p*2048 + (2*sigma(d,c)) ^ ((p&7)<<4), scaled 1/256
#pragma unroll
  for (int mi = 0; mi < 4; ++mi) {
#pragma unroll
    for (int ni = 0; ni < 4; ++ni) {
      const int p  = (mq * 2 + (mi >> 1)) * 4 + nq * 2 + (ni >> 1);
      const int cb = (mi & 1) * 16 + g * 4;
      const int d  = (ni & 1) * 16 + l15;
      const int kp = (((cb >> 2) & 1) << 2) | ((d & 1) << 3) | (((cb >> 3) & 1) << 4)
                   | (((d >> 1) & 7) << 5) | (((cb >> 4) & 1) << 8) | (((d >> 4) & 1) << 9);
      const int inner = (kp * 2) ^ ((p & 7) << 4);
      const fx4 s = acc[mi][ni] * 0.00390625f;
      u32x2 v;
      v[0] = cvtpk(s[0], s[1]);
      v[1] = cvtpk(s[2], s[3]);
      *(u32x2*)(o_sh + p * 2048 + inner) = v;
    }
  }
  __syncthreads();

  // ---- phase B: wave (zq = z'-tile of 32, kh = K-half of 512)
  {
    const int zq = wid & 3;
    const int kh = wid >> 2;
    const int p  = lane & 31;          // B col / A row (z'-local)
    const int h  = lane >> 5;

    const unsigned short* wp = w2T + zq * 32768 + h * 256 + p * 8;
    f32x16 accB = {};
#pragma unroll 8
    for (int ks2 = 0; ks2 < 32; ++ks2) {
      const int ks = kh * 32 + ks2;
      const bfx8 wf = *(const bfx8*)(wp + ks * 512);
      const bfx8 of = *(const bfx8*)(o_sh + p * 2048 + ((ks * 32 + h * 16) ^ ((p & 7) << 4)));
      accB = __builtin_amdgcn_mfma_f32_32x32x16_bf16(wf, of, accB, 0, 0, 0);
    }
    __syncthreads();   // all O reads done; o_sh reusable for partials

    // partial store: [kh][zq][(q*2+h)*32 + p] x 16B
#pragma unroll
    for (int q = 0; q < 4; ++q) {
      fx4 v = { accB[4 * q], accB[4 * q + 1], accB[4 * q + 2], accB[4 * q + 3] };
      *(fx4*)(o_sh + kh * 16384 + zq * 4096 + (((q * 2 + h) * 32 + p) << 4)) = v;
    }
  }
  __syncthreads();

  // ---- coop epilogue: sum K-halves + bias, coalesced f32 stores
  {
    const int pp = tid & 31;
    const int zblk = tid >> 5;          // 0..15 -> z' = zblk*8 .. +7
    const int zq2 = zblk >> 2, q2 = zblk & 3;
    const int b0 = zq2 * 4096 + ((q2 * 2) * 32 + pp) * 16;
    fx4 s0 = *(fx4*)(o_sh + b0)       + *(fx4*)(o_sh + 16384 + b0);
    fx4 s1 = *(fx4*)(o_sh + b0 + 512) + *(fx4*)(o_sh + 16384 + b0 + 512);
    const int z0 = zblk * 8;
    s0 += *(const fx4*)(bout + z0);
    s1 += *(const fx4*)(bout + z0 + 4);
    const int i = i0 + (pp >> 2), j = j0 + (pp & 3);
    float* op = out + ((i * SDIM + j) * CZ + z0);
    *(fx4*)op = s0;
    *(fx4*)(op + 4) = s1;
  }
}

extern "C" void kernel_launch(void* const* d_in, const int* in_sizes, int n_in,
                              void* d_out, int out_size, void* d_ws, size_t ws_size,
                              hipStream_t stream) {
  const float* m_si  = (const float*)d_in[0];
  const float* gamma = (const float*)d_in[1];
  const float* beta  = (const float*)d_in[2];
  const float* Wab   = (const float*)d_in[3];
  const float* Wout  = (const float*)d_in[4];
  const float* bout  = (const float*)d_in[5];
  float* out = (float*)d_out;

  char* ws = (char*)d_ws;
  unsigned short* a_t = (unsigned short*)ws;                    // 4 MB
  unsigned short* b_t = (unsigned short*)(ws + (4u << 20));     // 4 MB
  unsigned short* w2T = (unsigned short*)(ws + (8u << 20));     // 256 KB

  opm_prep<<<dim3(SDIM + 8), dim3(256), 0, stream>>>(m_si, gamma, beta, Wab, Wout, a_t, b_t, w2T);
  opm_main<<<dim3(2048), dim3(512), 0, stream>>>(a_t, b_t, w2T, bout, out);
}

// Round 4
// 90.643 us; speedup vs baseline: 1.8064x; 1.8064x over previous
//
#include <hip/hip_runtime.h>

#define SDIM 256
#define NSEQ 256
#define CDIM 32
#define CZ 128
#define IB 8
#define JB 4

typedef __bf16 bfx8 __attribute__((ext_vector_type(8)));
typedef float fx4 __attribute__((ext_vector_type(4)));
typedef float f32x16 __attribute__((ext_vector_type(16)));
typedef unsigned int u32x4 __attribute__((ext_vector_type(4)));

__device__ __forceinline__ unsigned short f2bf(float f) {
  unsigned int u = __float_as_uint(f);
  u += 0x7fffu + ((u >> 16) & 1u);
  return (unsigned short)(u >> 16);
}

__device__ __forceinline__ unsigned int cvtpk(float lo, float hi) {
  unsigned int r;
  asm("v_cvt_pk_bf16_f32 %0, %1, %2" : "=v"(r) : "v"(lo), "v"(hi));
  return r;
}

__device__ __forceinline__ void gload16(const void* g, void* l) {
  __builtin_amdgcn_global_load_lds((const __attribute__((address_space(1))) unsigned int*)g,
                                   (__attribute__((address_space(3))) unsigned int*)l,
                                   16, 0, 0);
}

// sigma(d,c): k' = c0 + 2*c1 + 4*c3 + 8*d[0:4] + 256*c2 + 512*c4
// -> 16B LDS chunk (k'[0:2]) = one lane's acc regs [8*c4 .. 8*c4+7]; sl = k'>>3 = d + 32*c2 + 64*c4

// ---------------- prep ----------------
__global__ __launch_bounds__(256) void opm_prep(
    const float* __restrict__ m_si, const float* __restrict__ gamma, const float* __restrict__ beta,
    const float* __restrict__ Wab, const float* __restrict__ Wout,
    unsigned short* __restrict__ a_t, unsigned short* __restrict__ b_t,
    unsigned short* __restrict__ w2T)
{
  const int b = blockIdx.x;
  const int t = threadIdx.x;
  if (b < SDIM) {
    __shared__ float wab[2048];
    __shared__ float gbuf[64];
    __shared__ __align__(16) char xbuf[32768];   // f32 [256][32] then bf16 [64][256]
    float* xin = (float*)xbuf;
    unsigned short* xt = (unsigned short*)xbuf;

    const float* msrc = m_si + b * 8192;
#pragma unroll
    for (int k = 0; k < 8; ++k) ((fx4*)xin)[t + k * 256] = ((const fx4*)msrc)[t + k * 256];
    for (int k = t; k < 2048; k += 256) wab[k] = Wab[k];
    if (t < 32) { gbuf[t] = gamma[t]; gbuf[32 + t] = beta[t]; }
    __syncthreads();

    float x[CDIM];
#pragma unroll
    for (int c = 0; c < CDIM; ++c) x[c] = xin[t * 32 + c];
    __syncthreads();   // xin reads done; xbuf reusable as xt

    float mu = 0.f;
#pragma unroll
    for (int c = 0; c < CDIM; ++c) mu += x[c];
    mu *= (1.f / CDIM);
    float var = 0.f;
#pragma unroll
    for (int c = 0; c < CDIM; ++c) { float d = x[c] - mu; var += d * d; }
    var *= (1.f / CDIM);
    const float inv = rsqrtf(var + 1e-5f);
#pragma unroll
    for (int c = 0; c < CDIM; ++c) x[c] = (x[c] - mu) * inv * gbuf[c] + gbuf[32 + c];

    for (int dp = 0; dp < 64; ++dp) {
      float s = 0.f;
#pragma unroll
      for (int c = 0; c < CDIM; ++c) s += x[c] * wab[dp * 32 + c];
      xt[dp * 256 + t] = f2bf(s);
    }
    __syncthreads();

    // coalesced writeout: 2048 x 16B chunks
#pragma unroll
    for (int k = 0; k < 8; ++k) {
      const int q = t + k * 256;
      const int row = q >> 5, cc = q & 31;
      const u32x4 v = *(const u32x4*)(xbuf + row * 512 + cc * 16);
      unsigned short* dst = (row < 32)
        ? (a_t + (b * 32 + row) * 256 + cc * 8)
        : (b_t + (b * 32 + (row - 32)) * 256 + cc * 8);
      *(u32x4*)dst = v;
    }
  } else {
    // w2T[dest], dest bits: e[0:2], zl[3:7], h[8], ks[9:14], zt[15:16]
    // holds Wout[z = zt*32+zl][k = c*32+d] with k' = ks*16 + h*8 + e, sigma^-1:
    //   c = k'[0] + 2k'[1] + 4k'[8] + 8k'[2] + 16k'[9];  d = (k'>>3)&31
    const int base = ((b - SDIM) * 256 + t) * 64;
#pragma unroll 8
    for (int u = 0; u < 64; ++u) {
      const int dest = base + u;
      const int e  = dest & 7;
      const int zl = (dest >> 3) & 31;
      const int h  = (dest >> 8) & 1;
      const int ks = (dest >> 9) & 63;
      const int zt = dest >> 15;
      const int kp = ks * 16 + h * 8 + e;
      const int c = (kp & 3) | (((kp >> 8) & 1) << 2) | (((kp >> 2) & 1) << 3) | (((kp >> 9) & 1) << 4);
      const int d = (kp >> 3) & 31;
      const int z = zt * 32 + zl;
      w2T[dest] = f2bf(Wout[z * 1024 + c * CDIM + d]);
    }
  }
}

// ---------------- main: 8x4 (i,j) tiles = 32 pairs/block, 32x32x16 MFMA ----------------
__global__ __launch_bounds__(512, 4) void opm_main(
    const unsigned short* __restrict__ a_t, const unsigned short* __restrict__ b_t,
    const unsigned short* __restrict__ w2T, const float* __restrict__ bout,
    float* __restrict__ out)
{
  // O [0,64K) overlays staging: A0 [16K,32K) A1 [32K,48K) B0 [48K,56K) B1 [56K,64K)
  __shared__ __align__(16) char smem[65536];
  char* o_sh = smem;

  const int tid = threadIdx.x;
  const int lane = tid & 63;
  const int wid = tid >> 6;           // 0..7
  const int l31 = lane & 31;
  const int h = lane >> 5;

  const int bxr = blockIdx.x;
  const int bx = (bxr & 7) * 256 + (bxr >> 3);   // bijective XCD swizzle (2048%8==0)
  const int i0 = (bx >> 6) * IB;
  const int j0 = (bx & 63) * JB;

  const int wm = wid >> 1;            // 0..3: M 64-row group
  const int wn = wid & 1;             // 0..1: N 64-row group
  const int wbase = wid * 1024;       // wave-uniform LDS staging offset

  f32x16 acc00 = {}, acc01 = {}, acc10 = {}, acc11 = {};

  auto STAGE = [&](int buf, int nc) {
    const int nbase = nc * 32;
    char* A = smem + 16384 + buf * 16384;
    char* B = smem + 49152 + buf * 8192;
#pragma unroll
    for (int pass = 0; pass < 2; ++pass) {
      const int q = pass * 512 + tid;
      const int row = q >> 2;
      const int gs = (q & 3) ^ (row & 3);
      const unsigned short* src = a_t + ((i0 + (row >> 5)) * 32 + (row & 31)) * 256 + nbase + gs * 8;
      gload16(src, A + pass * 8192 + wbase);
    }
    {
      const int q = tid;
      const int row = q >> 2;
      const int gs = (q & 3) ^ (row & 3);
      const unsigned short* src = b_t + ((j0 + (row >> 5)) * 32 + (row & 31)) * 256 + nbase + gs * 8;
      gload16(src, B + wbase);
    }
  };

  auto COMPUTE = [&](int buf) {
    char* A = smem + 16384 + buf * 16384;
    char* B = smem + 49152 + buf * 8192;
#pragma unroll
    for (int ks = 0; ks < 2; ++ks) {
      const int s = ks * 2 + h;
      bfx8 af0, af1, bf0, bf1;
      { const int r = wm * 64 + l31;      af0 = *(const bfx8*)(A + r * 64 + ((s ^ (r & 3)) << 4)); }
      { const int r = wm * 64 + 32 + l31; af1 = *(const bfx8*)(A + r * 64 + ((s ^ (r & 3)) << 4)); }
      { const int r = wn * 64 + l31;      bf0 = *(const bfx8*)(B + r * 64 + ((s ^ (r & 3)) << 4)); }
      { const int r = wn * 64 + 32 + l31; bf1 = *(const bfx8*)(B + r * 64 + ((s ^ (r & 3)) << 4)); }
      __builtin_amdgcn_s_setprio(1);
      acc00 = __builtin_amdgcn_mfma_f32_32x32x16_bf16(af0, bf0, acc00, 0, 0, 0);
      acc01 = __builtin_amdgcn_mfma_f32_32x32x16_bf16(af0, bf1, acc01, 0, 0, 0);
      acc10 = __builtin_amdgcn_mfma_f32_32x32x16_bf16(af1, bf0, acc10, 0, 0, 0);
      acc11 = __builtin_amdgcn_mfma_f32_32x32x16_bf16(af1, bf1, acc11, 0, 0, 0);
      __builtin_amdgcn_s_setprio(0);
    }
  };

  STAGE(0, 0);
#pragma unroll 2
  for (int t = 0; t < 8; ++t) {
    if (t < 7) {
      STAGE((t + 1) & 1, t + 1);
      asm volatile("s_waitcnt vmcnt(3)" ::: "memory");
    } else {
      asm volatile("s_waitcnt vmcnt(0)" ::: "memory");
    }
    __builtin_amdgcn_s_barrier();
    asm volatile("" ::: "memory");
    COMPUTE(t & 1);
    asm volatile("s_waitcnt lgkmcnt(0)" ::: "memory");
    __builtin_amdgcn_s_barrier();
  }

  // ---- O -> LDS: pair p at [p*2048 + ((d + 32*c2 + 64*c4) ^ (p&7))*16]
  {
    const f32x16 av[4] = { acc00 * 0.00390625f, acc01 * 0.00390625f,
                           acc10 * 0.00390625f, acc11 * 0.00390625f };
#pragma unroll
    for (int mi = 0; mi < 2; ++mi) {
#pragma unroll
      for (int ni = 0; ni < 2; ++ni) {
        const f32x16 a = av[mi * 2 + ni];
        const int p = (wm * 2 + mi) * 4 + (wn * 2 + ni);
#pragma unroll
        for (int c4 = 0; c4 < 2; ++c4) {
          const int sl = l31 + 32 * h + 64 * c4;
          u32x4 v;
          v[0] = cvtpk(a[8 * c4 + 0], a[8 * c4 + 1]);
          v[1] = cvtpk(a[8 * c4 + 2], a[8 * c4 + 3]);
          v[2] = cvtpk(a[8 * c4 + 4], a[8 * c4 + 5]);
          v[3] = cvtpk(a[8 * c4 + 6], a[8 * c4 + 7]);
          *(u32x4*)(o_sh + p * 2048 + ((sl ^ (p & 7)) << 4)) = v;
        }
      }
    }
  }
  __syncthreads();

  // ---- phase B: wave (zt = z'-tile of 32, kh = K-half of 512); all 32 pairs per wave
  {
    const int zt = wid & 3;
    const int kh = wid >> 2;
    const unsigned short* wp = w2T + (zt << 15) + (h << 8) + (l31 << 3);
    f32x16 accB = {};
#pragma unroll 8
    for (int ks2 = 0; ks2 < 32; ++ks2) {
      const int ksg = kh * 32 + ks2;
      const bfx8 wf = *(const bfx8*)(wp + (ksg << 9));
      const int sl = 2 * ksg + h;
      const bfx8 of = *(const bfx8*)(o_sh + l31 * 2048 + ((sl ^ (l31 & 7)) << 4));
      accB = __builtin_amdgcn_mfma_f32_32x32x16_bf16(wf, of, accB, 0, 0, 0);
    }
    __syncthreads();   // all O reads done; o_sh front reusable for partials

    // partial fx4 at [kh][zt][s*32 + p], s = g2*2 + h  (z_local = 4s..4s+3)
#pragma unroll
    for (int g2 = 0; g2 < 4; ++g2) {
      fx4 v = { accB[4 * g2], accB[4 * g2 + 1], accB[4 * g2 + 2], accB[4 * g2 + 3] };
      const int s = g2 * 2 + h;
      *(fx4*)(o_sh + kh * 16384 + zt * 4096 + ((s * 32 + l31) << 4)) = v;
    }
  }
  __syncthreads();

  // ---- coop epilogue: sum K-halves + bias
#pragma unroll
  for (int k = 0; k < 2; ++k) {
    const int v = tid + k * 512;
    const int zt2 = v >> 8, s2 = (v >> 5) & 7, pp = v & 31;
    const int off = zt2 * 4096 + ((s2 * 32 + pp) << 4);
    fx4 r = *(fx4*)(o_sh + off) + *(fx4*)(o_sh + 16384 + off);
    const int z0 = zt2 * 32 + s2 * 4;
    r += *(const fx4*)(bout + z0);
    const int i = i0 + (pp >> 2), j = j0 + (pp & 3);
    *(fx4*)(out + (i * SDIM + j) * CZ + z0) = r;
  }
}

extern "C" void kernel_launch(void* const* d_in, const int* in_sizes, int n_in,
                              void* d_out, int out_size, void* d_ws, size_t ws_size,
                              hipStream_t stream) {
  const float* m_si  = (const float*)d_in[0];
  const float* gamma = (const float*)d_in[1];
  const float* beta  = (const float*)d_in[2];
  const float* Wab   = (const float*)d_in[3];
  const float* Wout  = (const float*)d_in[4];
  const float* bout  = (const float*)d_in[5];
  float* out = (float*)d_out;

  char* ws = (char*)d_ws;
  unsigned short* a_t = (unsigned short*)ws;                    // 4 MB
  unsigned short* b_t = (unsigned short*)(ws + (4u << 20));     // 4 MB
  unsigned short* w2T = (unsigned short*)(ws + (8u << 20));     // 256 KB

  opm_prep<<<dim3(SDIM + 8), dim3(256), 0, stream>>>(m_si, gamma, beta, Wab, Wout, a_t, b_t, w2T);
  opm_main<<<dim3(2048), dim3(512), 0, stream>>>(a_t, b_t, w2T, bout, out);
}

// Round 5
// 87.252 us; speedup vs baseline: 1.8766x; 1.0389x over previous
//
#include <hip/hip_runtime.h>

#define SDIM 256
#define NSEQ 256
#define CDIM 32
#define CZ 128
#define IB 8
#define JB 4

typedef __bf16 bfx8 __attribute__((ext_vector_type(8)));
typedef float fx4 __attribute__((ext_vector_type(4)));
typedef float f32x16 __attribute__((ext_vector_type(16)));
typedef unsigned int u32x4 __attribute__((ext_vector_type(4)));

__device__ __forceinline__ unsigned short f2bf(float f) {
  unsigned int u = __float_as_uint(f);
  u += 0x7fffu + ((u >> 16) & 1u);
  return (unsigned short)(u >> 16);
}

__device__ __forceinline__ unsigned int cvtpk(float lo, float hi) {
  unsigned int r;
  asm("v_cvt_pk_bf16_f32 %0, %1, %2" : "=v"(r) : "v"(lo), "v"(hi));
  return r;
}

__device__ __forceinline__ void gload16(const void* g, void* l) {
  __builtin_amdgcn_global_load_lds((const __attribute__((address_space(1))) unsigned int*)g,
                                   (__attribute__((address_space(3))) unsigned int*)l,
                                   16, 0, 0);
}

// sigma(d,c): k' = c0 + 2*c1 + 4*c3 + 8*d[0:4] + 256*c2 + 512*c4
// -> 16B LDS chunk (k'[0:2]) = one lane's acc regs [8*c4 .. 8*c4+7]; sl = k'>>3 = d + 32*c2 + 64*c4

// ---------------- prep ----------------
// blocks [0,512): LN + half of ab-projection (dph: 0->a, 1->b), per s
// blocks [512,520): W_out -> w2T repack
__global__ __launch_bounds__(256) void opm_prep(
    const float* __restrict__ m_si, const float* __restrict__ gamma, const float* __restrict__ beta,
    const float* __restrict__ Wab, const float* __restrict__ Wout,
    unsigned short* __restrict__ a_t, unsigned short* __restrict__ b_t,
    unsigned short* __restrict__ w2T)
{
  const int b = blockIdx.x;
  const int t = threadIdx.x;
  if (b < 2 * SDIM) {
    const int s = b >> 1, dph = b & 1;
    __shared__ float wab[1024];
    __shared__ float gbuf[64];
    __shared__ __align__(16) char xbuf[36864];  // f32 [256][36-stride] then bf16 [32][256]
    float* xin = (float*)xbuf;
    unsigned short* xt = (unsigned short*)xbuf;

    const float* msrc = m_si + s * 8192;
#pragma unroll
    for (int k = 0; k < 8; ++k) {
      const int q = t + k * 256;          // fx4 index in [0,2048)
      const int row = q >> 3, cq = q & 7; // row n, col-quad
      ((fx4*)xin)[row * 9 + cq] = ((const fx4*)msrc)[q];
    }
    for (int k = t; k < 1024; k += 256) wab[k] = Wab[dph * 1024 + k];
    if (t < 32) { gbuf[t] = gamma[t]; gbuf[32 + t] = beta[t]; }
    __syncthreads();

    float x[CDIM];
#pragma unroll
    for (int c = 0; c < CDIM; ++c) x[c] = xin[t * 36 + c];
    __syncthreads();   // xin reads done; xbuf reusable as xt

    float mu = 0.f;
#pragma unroll
    for (int c = 0; c < CDIM; ++c) mu += x[c];
    mu *= (1.f / CDIM);
    float var = 0.f;
#pragma unroll
    for (int c = 0; c < CDIM; ++c) { float d = x[c] - mu; var += d * d; }
    var *= (1.f / CDIM);
    const float inv = rsqrtf(var + 1e-5f);
#pragma unroll
    for (int c = 0; c < CDIM; ++c) x[c] = (x[c] - mu) * inv * gbuf[c] + gbuf[32 + c];

    for (int dp = 0; dp < 32; ++dp) {
      float sum = 0.f;
#pragma unroll
      for (int c = 0; c < CDIM; ++c) sum += x[c] * wab[dp * 32 + c];
      xt[dp * 256 + t] = f2bf(sum);
    }
    __syncthreads();

    unsigned short* outb = dph ? b_t : a_t;
#pragma unroll
    for (int k = 0; k < 4; ++k) {
      const int q = t + k * 256;          // 0..1023 16B chunks
      const int row = q >> 5, cc = q & 31;
      *(u32x4*)(outb + (s * 32 + row) * 256 + cc * 8) = *(const u32x4*)(xbuf + row * 512 + cc * 16);
    }
  } else {
    // w2T[dest], dest bits: e[0:2], zl[3:7], h[8], ks[9:14], zt[15:16]
    const int base = ((b - 2 * SDIM) * 256 + t) * 64;
#pragma unroll 8
    for (int u = 0; u < 64; ++u) {
      const int dest = base + u;
      const int e  = dest & 7;
      const int zl = (dest >> 3) & 31;
      const int h  = (dest >> 8) & 1;
      const int ks = (dest >> 9) & 63;
      const int zt = dest >> 15;
      const int kp = ks * 16 + h * 8 + e;
      const int c = (kp & 3) | (((kp >> 8) & 1) << 2) | (((kp >> 2) & 1) << 3) | (((kp >> 9) & 1) << 4);
      const int d = (kp >> 3) & 31;
      const int z = zt * 32 + zl;
      w2T[dest] = f2bf(Wout[z * 1024 + c * CDIM + d]);
    }
  }
}

// ---------------- main: 8x4 (i,j) tiles = 32 pairs/block, 32x32x16 MFMA ----------------
__global__ __launch_bounds__(512, 4) void opm_main(
    const unsigned short* __restrict__ a_t, const unsigned short* __restrict__ b_t,
    const unsigned short* __restrict__ w2T, const float* __restrict__ bout,
    float* __restrict__ out)
{
  // O [0,64K) overlays staging: A0 [16K,32K) A1 [32K,48K) B0 [48K,56K) B1 [56K,64K)
  __shared__ __align__(16) char smem[65536];
  char* o_sh = smem;

  const int tid = threadIdx.x;
  const int lane = tid & 63;
  const int wid = tid >> 6;           // 0..7
  const int l31 = lane & 31;
  const int h = lane >> 5;

  const int bxr = blockIdx.x;
  const int bx = (bxr & 7) * 256 + (bxr >> 3);   // bijective XCD swizzle (2048%8==0)
  const int i0 = (bx >> 6) * IB;
  const int j0 = (bx & 63) * JB;

  const int wm = wid >> 1;            // 0..3: M 64-row group
  const int wn = wid & 1;             // 0..1: N 64-row group
  const int wbase = wid * 1024;       // wave-uniform LDS staging offset

  f32x16 acc00 = {}, acc01 = {}, acc10 = {}, acc11 = {};

  // chunk q (16B) lives at LDS offset q*16 (row=q>>2, slot=q&3) and holds
  // global n-group gs = (q&3) ^ ((q>>3)&3)   [slot-XOR keyed by row>>1]
  auto STAGE = [&](int buf, int nc) {
    const int nbase = nc * 32;
    char* A = smem + 16384 + buf * 16384;
    char* B = smem + 49152 + buf * 8192;
#pragma unroll
    for (int pass = 0; pass < 2; ++pass) {
      const int q = pass * 512 + tid;
      const int row = q >> 2;
      const int gs = (q & 3) ^ ((q >> 3) & 3);
      const unsigned short* src = a_t + ((i0 + (row >> 5)) * 32 + (row & 31)) * 256 + nbase + gs * 8;
      gload16(src, A + pass * 8192 + wbase);
    }
    {
      const int q = tid;
      const int row = q >> 2;
      const int gs = (q & 3) ^ ((q >> 3) & 3);
      const unsigned short* src = b_t + ((j0 + (row >> 5)) * 32 + (row & 31)) * 256 + nbase + gs * 8;
      gload16(src, B + wbase);
    }
  };

  auto COMPUTE = [&](int buf) {
    char* A = smem + 16384 + buf * 16384;
    char* B = smem + 49152 + buf * 8192;
#pragma unroll
    for (int ks = 0; ks < 2; ++ks) {
      const int s = ks * 2 + h;
      bfx8 af0, af1, bf0, bf1;
      { const int r = wm * 64 + l31;      af0 = *(const bfx8*)(A + r * 64 + (((s ^ (r >> 1)) & 3) << 4)); }
      { const int r = wm * 64 + 32 + l31; af1 = *(const bfx8*)(A + r * 64 + (((s ^ (r >> 1)) & 3) << 4)); }
      { const int r = wn * 64 + l31;      bf0 = *(const bfx8*)(B + r * 64 + (((s ^ (r >> 1)) & 3) << 4)); }
      { const int r = wn * 64 + 32 + l31; bf1 = *(const bfx8*)(B + r * 64 + (((s ^ (r >> 1)) & 3) << 4)); }
      __builtin_amdgcn_s_setprio(1);
      acc00 = __builtin_amdgcn_mfma_f32_32x32x16_bf16(af0, bf0, acc00, 0, 0, 0);
      acc01 = __builtin_amdgcn_mfma_f32_32x32x16_bf16(af0, bf1, acc01, 0, 0, 0);
      acc10 = __builtin_amdgcn_mfma_f32_32x32x16_bf16(af1, bf0, acc10, 0, 0, 0);
      acc11 = __builtin_amdgcn_mfma_f32_32x32x16_bf16(af1, bf1, acc11, 0, 0, 0);
      __builtin_amdgcn_s_setprio(0);
    }
  };

  STAGE(0, 0);
#pragma unroll 2
  for (int t = 0; t < 8; ++t) {
    if (t < 7) {
      STAGE((t + 1) & 1, t + 1);
      asm volatile("s_waitcnt vmcnt(3)" ::: "memory");
    } else {
      asm volatile("s_waitcnt vmcnt(0)" ::: "memory");
    }
    __builtin_amdgcn_s_barrier();
    asm volatile("" ::: "memory");
    COMPUTE(t & 1);
    asm volatile("s_waitcnt lgkmcnt(0)" ::: "memory");
    __builtin_amdgcn_s_barrier();
  }

  // ---- O -> LDS: pair p at [p*2048 + ((d + 32*c2 + 64*c4) ^ (p&7))*16]
  {
    const f32x16 av[4] = { acc00 * 0.00390625f, acc01 * 0.00390625f,
                           acc10 * 0.00390625f, acc11 * 0.00390625f };
#pragma unroll
    for (int mi = 0; mi < 2; ++mi) {
#pragma unroll
      for (int ni = 0; ni < 2; ++ni) {
        const f32x16 a = av[mi * 2 + ni];
        const int p = (wm * 2 + mi) * 4 + (wn * 2 + ni);
#pragma unroll
        for (int c4 = 0; c4 < 2; ++c4) {
          const int sl = l31 + 32 * h + 64 * c4;
          u32x4 v;
          v[0] = cvtpk(a[8 * c4 + 0], a[8 * c4 + 1]);
          v[1] = cvtpk(a[8 * c4 + 2], a[8 * c4 + 3]);
          v[2] = cvtpk(a[8 * c4 + 4], a[8 * c4 + 5]);
          v[3] = cvtpk(a[8 * c4 + 6], a[8 * c4 + 7]);
          *(u32x4*)(o_sh + p * 2048 + ((sl ^ (p & 7)) << 4)) = v;
        }
      }
    }
  }
  __syncthreads();

  // ---- phase B: wave (zt = z'-tile of 32, kh = K-half of 512); explicit depth-1 prefetch
  {
    const int zt = wid & 3;
    const int kh = wid >> 2;
    const unsigned short* wp = w2T + (zt << 15) + (h << 8) + (l31 << 3);
    f32x16 accB = {};
    int ksg = kh * 32;
    bfx8 wfA = *(const bfx8*)(wp + (ksg << 9));
    bfx8 ofA = *(const bfx8*)(o_sh + l31 * 2048 + (((2 * ksg + h) ^ (l31 & 7)) << 4));
#pragma unroll
    for (int it = 0; it < 31; ++it) {
      const int kn = kh * 32 + it + 1;
      const bfx8 wfB = *(const bfx8*)(wp + (kn << 9));
      const bfx8 ofB = *(const bfx8*)(o_sh + l31 * 2048 + (((2 * kn + h) ^ (l31 & 7)) << 4));
      accB = __builtin_amdgcn_mfma_f32_32x32x16_bf16(wfA, ofA, accB, 0, 0, 0);
      wfA = wfB; ofA = ofB;
    }
    accB = __builtin_amdgcn_mfma_f32_32x32x16_bf16(wfA, ofA, accB, 0, 0, 0);
    __syncthreads();   // all O reads done; o_sh front reusable for partials

    // partial fx4 at [kh][zt][s*32 + p], s = g2*2 + h  (z_local = 4s..4s+3)
#pragma unroll
    for (int g2 = 0; g2 < 4; ++g2) {
      fx4 v = { accB[4 * g2], accB[4 * g2 + 1], accB[4 * g2 + 2], accB[4 * g2 + 3] };
      const int s = g2 * 2 + h;
      *(fx4*)(o_sh + kh * 16384 + zt * 4096 + ((s * 32 + l31) << 4)) = v;
    }
  }
  __syncthreads();

  // ---- coop epilogue: sum K-halves + bias
#pragma unroll
  for (int k = 0; k < 2; ++k) {
    const int v = tid + k * 512;
    const int zt2 = v >> 8, s2 = (v >> 5) & 7, pp = v & 31;
    const int off = zt2 * 4096 + ((s2 * 32 + pp) << 4);
    fx4 r = *(fx4*)(o_sh + off) + *(fx4*)(o_sh + 16384 + off);
    const int z0 = zt2 * 32 + s2 * 4;
    r += *(const fx4*)(bout + z0);
    const int i = i0 + (pp >> 2), j = j0 + (pp & 3);
    *(fx4*)(out + (i * SDIM + j) * CZ + z0) = r;
  }
}

extern "C" void kernel_launch(void* const* d_in, const int* in_sizes, int n_in,
                              void* d_out, int out_size, void* d_ws, size_t ws_size,
                              hipStream_t stream) {
  const float* m_si  = (const float*)d_in[0];
  const float* gamma = (const float*)d_in[1];
  const float* beta  = (const float*)d_in[2];
  const float* Wab   = (const float*)d_in[3];
  const float* Wout  = (const float*)d_in[4];
  const float* bout  = (const float*)d_in[5];
  float* out = (float*)d_out;

  char* ws = (char*)d_ws;
  unsigned short* a_t = (unsigned short*)ws;                    // 4 MB
  unsigned short* b_t = (unsigned short*)(ws + (4u << 20));     // 4 MB
  unsigned short* w2T = (unsigned short*)(ws + (8u << 20));     // 256 KB

  opm_prep<<<dim3(2 * SDIM + 8), dim3(256), 0, stream>>>(m_si, gamma, beta, Wab, Wout, a_t, b_t, w2T);
  opm_main<<<dim3(2048), dim3(512), 0, stream>>>(a_t, b_t, w2T, bout, out);
}

// Round 6
// 85.851 us; speedup vs baseline: 1.9073x; 1.0163x over previous
//
#include <hip/hip_runtime.h>

#define SDIM 256
#define NSEQ 256
#define CDIM 32
#define CZ 128
#define IB 8
#define JB 4

typedef __bf16 bfx8 __attribute__((ext_vector_type(8)));
typedef float fx4 __attribute__((ext_vector_type(4)));
typedef float f32x16 __attribute__((ext_vector_type(16)));
typedef unsigned int u32x4 __attribute__((ext_vector_type(4)));

__device__ __forceinline__ unsigned short f2bf(float f) {
  unsigned int u = __float_as_uint(f);
  u += 0x7fffu + ((u >> 16) & 1u);
  return (unsigned short)(u >> 16);
}

__device__ __forceinline__ unsigned int cvtpk(float lo, float hi) {
  unsigned int r;
  asm("v_cvt_pk_bf16_f32 %0, %1, %2" : "=v"(r) : "v"(lo), "v"(hi));
  return r;
}

__device__ __forceinline__ void gload16(const void* g, void* l) {
  __builtin_amdgcn_global_load_lds((const __attribute__((address_space(1))) unsigned int*)g,
                                   (__attribute__((address_space(3))) unsigned int*)l,
                                   16, 0, 0);
}

// sigma(d,c): k' = c0 + 2*c1 + 4*c3 + 8*d[0:4] + 256*c2 + 512*c4
// -> 16B LDS chunk (k'[0:2]) = one lane's acc regs [8*c4 .. 8*c4+7]; sl = k'>>3 = d + 32*c2 + 64*c4

// ---------------- prep ----------------
// blocks [0,512): LN + half of ab-projection (dph: 0->a, 1->b), per s
// blocks [512,520): W_out -> w2T repack via LDS transpose (16 z-rows each)
__global__ __launch_bounds__(256) void opm_prep(
    const float* __restrict__ m_si, const float* __restrict__ gamma, const float* __restrict__ beta,
    const float* __restrict__ Wab, const float* __restrict__ Wout,
    unsigned short* __restrict__ a_t, unsigned short* __restrict__ b_t,
    unsigned short* __restrict__ w2T)
{
  __shared__ __align__(16) char shbuf[41216];
  const int b = blockIdx.x;
  const int t = threadIdx.x;
  if (b < 2 * SDIM) {
    float* xin = (float*)shbuf;                      // f32 [256][36] (padded)
    unsigned short* xt = (unsigned short*)shbuf;     // later: bf16 [32][256]
    fx4* wab4 = (fx4*)(shbuf + 36864);               // [32][8]
    float* gbuf = (float*)(shbuf + 36864 + 4096);    // [64]
    const int s = b >> 1, dph = b & 1;

    const float* msrc = m_si + s * 8192;
#pragma unroll
    for (int k = 0; k < 8; ++k) {
      const int q = t + k * 256;
      ((fx4*)xin)[(q >> 3) * 9 + (q & 7)] = ((const fx4*)msrc)[q];
    }
    wab4[t & 255] = ((const fx4*)(Wab + dph * 1024))[t & 255];
    if (t < 32) { gbuf[t] = gamma[t]; gbuf[32 + t] = beta[t]; }
    __syncthreads();

    float x[CDIM];
#pragma unroll
    for (int c = 0; c < CDIM; ++c) x[c] = xin[t * 36 + c];
    __syncthreads();   // xin reads done; shbuf reusable as xt

    float mu = 0.f;
#pragma unroll
    for (int c = 0; c < CDIM; ++c) mu += x[c];
    mu *= (1.f / CDIM);
    float var = 0.f;
#pragma unroll
    for (int c = 0; c < CDIM; ++c) { float d = x[c] - mu; var += d * d; }
    var *= (1.f / CDIM);
    const float inv = rsqrtf(var + 1e-5f);
    fx4 xv[8];
#pragma unroll
    for (int cq = 0; cq < 8; ++cq) {
      fx4 v;
#pragma unroll
      for (int j = 0; j < 4; ++j) {
        const int c = cq * 4 + j;
        v[j] = (x[c] - mu) * inv * gbuf[c] + gbuf[32 + c];
      }
      xv[cq] = v;
    }

    for (int dp = 0; dp < 32; ++dp) {
      fx4 a = xv[0] * wab4[dp * 8];
#pragma unroll
      for (int cq = 1; cq < 8; ++cq) a += xv[cq] * wab4[dp * 8 + cq];
      xt[dp * 256 + t] = f2bf(a[0] + a[1] + a[2] + a[3]);
    }
    __syncthreads();

    unsigned short* outb = dph ? b_t : a_t;
#pragma unroll
    for (int k = 0; k < 4; ++k) {
      const int q = t + k * 256;          // 16B chunks
      const int row = q >> 5, cc = q & 31;
      *(u32x4*)(outb + (s * 32 + row) * 256 + cc * 8) = *(const u32x4*)(shbuf + row * 512 + cc * 16);
    }
  } else {
    // repack: block covers 16 z rows. coalesced load -> LDS bf16 [16][1024] -> gather-write
    unsigned short* lin = (unsigned short*)shbuf;    // 32KB
    const int blk = b - 2 * SDIM;                    // 0..7
    const float* wsrc = Wout + blk * 16384;
#pragma unroll
    for (int jj = 0; jj < 16; ++jj) {
      const int q = t + jj * 256;                    // fx4 id
      const fx4 v = ((const fx4*)wsrc)[q];
      unsigned short* dst = lin + q * 4;
      dst[0] = f2bf(v[0]); dst[1] = f2bf(v[1]); dst[2] = f2bf(v[2]); dst[3] = f2bf(v[3]);
    }
    __syncthreads();
    const int zt = blk >> 1;
    const int zlbase = (blk & 1) * 16;
#pragma unroll
    for (int w = 0; w < 8; ++w) {
      const int id = t + w * 256;        // (zll = id&15, h = (id>>4)&1, ks = id>>5)
      const int zll = id & 15;
      const int h  = (id >> 4) & 1;
      const int ks = id >> 5;
      unsigned short vals[8];
#pragma unroll
      for (int e = 0; e < 8; ++e) {
        const int kp = ks * 16 + h * 8 + e;
        const int c = (kp & 3) | (((kp >> 8) & 1) << 2) | (((kp >> 2) & 1) << 3) | (((kp >> 9) & 1) << 4);
        const int d = (kp >> 3) & 31;
        vals[e] = lin[zll * 1024 + c * CDIM + d];
      }
      const int dest = (zt << 15) + (ks << 9) + (h << 8) + ((zlbase + zll) << 3);
      *(u32x4*)(w2T + dest) = *(const u32x4*)vals;
    }
  }
}

// ---------------- main: 8x4 (i,j) tiles = 32 pairs/block, 32x32x16 MFMA ----------------
__global__ __launch_bounds__(512, 4) void opm_main(
    const unsigned short* __restrict__ a_t, const unsigned short* __restrict__ b_t,
    const unsigned short* __restrict__ w2T, const float* __restrict__ bout,
    float* __restrict__ out)
{
  // O [0,64K) overlays staging: A0 [16K,32K) A1 [32K,48K) B0 [48K,56K) B1 [56K,64K)
  __shared__ __align__(16) char smem[65536];
  char* o_sh = smem;

  const int tid = threadIdx.x;
  const int lane = tid & 63;
  const int wid = tid >> 6;           // 0..7
  const int l31 = lane & 31;
  const int h = lane >> 5;

  const int bxr = blockIdx.x;
  const int bx = (bxr & 7) * 256 + (bxr >> 3);   // bijective XCD swizzle (2048%8==0)
  const int i0 = (bx >> 6) * IB;
  const int j0 = (bx & 63) * JB;

  const int wm = wid >> 1;            // 0..3: M 64-row group
  const int wn = wid & 1;             // 0..1: N 64-row group
  const int wbase = wid * 1024;       // wave-uniform LDS staging offset

  f32x16 acc00 = {}, acc01 = {}, acc10 = {}, acc11 = {};

  // chunk q (16B) at LDS offset q*16 holds global n-group gs = (q&3) ^ ((q>>3)&3)
  auto STAGE = [&](int buf, int nc) {
    const int nbase = nc * 32;
    char* A = smem + 16384 + buf * 16384;
    char* B = smem + 49152 + buf * 8192;
#pragma unroll
    for (int pass = 0; pass < 2; ++pass) {
      const int q = pass * 512 + tid;
      const int row = q >> 2;
      const int gs = (q & 3) ^ ((q >> 3) & 3);
      const unsigned short* src = a_t + ((i0 + (row >> 5)) * 32 + (row & 31)) * 256 + nbase + gs * 8;
      gload16(src, A + pass * 8192 + wbase);
    }
    {
      const int q = tid;
      const int row = q >> 2;
      const int gs = (q & 3) ^ ((q >> 3) & 3);
      const unsigned short* src = b_t + ((j0 + (row >> 5)) * 32 + (row & 31)) * 256 + nbase + gs * 8;
      gload16(src, B + wbase);
    }
  };

  auto COMPUTE = [&](int buf) {
    char* A = smem + 16384 + buf * 16384;
    char* B = smem + 49152 + buf * 8192;
#pragma unroll
    for (int ks = 0; ks < 2; ++ks) {
      const int s = ks * 2 + h;
      bfx8 af0, af1, bf0, bf1;
      { const int r = wm * 64 + l31;      af0 = *(const bfx8*)(A + r * 64 + (((s ^ (r >> 1)) & 3) << 4)); }
      { const int r = wm * 64 + 32 + l31; af1 = *(const bfx8*)(A + r * 64 + (((s ^ (r >> 1)) & 3) << 4)); }
      { const int r = wn * 64 + l31;      bf0 = *(const bfx8*)(B + r * 64 + (((s ^ (r >> 1)) & 3) << 4)); }
      { const int r = wn * 64 + 32 + l31; bf1 = *(const bfx8*)(B + r * 64 + (((s ^ (r >> 1)) & 3) << 4)); }
      __builtin_amdgcn_s_setprio(1);
      acc00 = __builtin_amdgcn_mfma_f32_32x32x16_bf16(af0, bf0, acc00, 0, 0, 0);
      acc01 = __builtin_amdgcn_mfma_f32_32x32x16_bf16(af0, bf1, acc01, 0, 0, 0);
      acc10 = __builtin_amdgcn_mfma_f32_32x32x16_bf16(af1, bf0, acc10, 0, 0, 0);
      acc11 = __builtin_amdgcn_mfma_f32_32x32x16_bf16(af1, bf1, acc11, 0, 0, 0);
      __builtin_amdgcn_s_setprio(0);
    }
  };

  STAGE(0, 0);
#pragma unroll 2
  for (int t = 0; t < 8; ++t) {
    if (t < 7) {
      STAGE((t + 1) & 1, t + 1);
      asm volatile("s_waitcnt vmcnt(3)" ::: "memory");
    } else {
      asm volatile("s_waitcnt vmcnt(0)" ::: "memory");
    }
    __builtin_amdgcn_s_barrier();
    asm volatile("" ::: "memory");
    COMPUTE(t & 1);
    asm volatile("s_waitcnt lgkmcnt(0)" ::: "memory");
    __builtin_amdgcn_s_barrier();
  }

  // ---- O -> LDS: pair p at [p*2048 + ((d + 32*c2 + 64*c4) ^ (p&7))*16]
  {
    const f32x16 av[4] = { acc00 * 0.00390625f, acc01 * 0.00390625f,
                           acc10 * 0.00390625f, acc11 * 0.00390625f };
#pragma unroll
    for (int mi = 0; mi < 2; ++mi) {
#pragma unroll
      for (int ni = 0; ni < 2; ++ni) {
        const f32x16 a = av[mi * 2 + ni];
        const int p = (wm * 2 + mi) * 4 + (wn * 2 + ni);
#pragma unroll
        for (int c4 = 0; c4 < 2; ++c4) {
          const int sl = l31 + 32 * h + 64 * c4;
          u32x4 v;
          v[0] = cvtpk(a[8 * c4 + 0], a[8 * c4 + 1]);
          v[1] = cvtpk(a[8 * c4 + 2], a[8 * c4 + 3]);
          v[2] = cvtpk(a[8 * c4 + 4], a[8 * c4 + 5]);
          v[3] = cvtpk(a[8 * c4 + 6], a[8 * c4 + 7]);
          *(u32x4*)(o_sh + p * 2048 + ((sl ^ (p & 7)) << 4)) = v;
        }
      }
    }
  }
  __syncthreads();

  // ---- phase B: wave (zt = z'-tile of 32, kh = K-half of 512); depth-4/2 prefetch
  {
    const int zt = wid & 3;
    const int kh = wid >> 2;
    const unsigned short* wp = w2T + (zt << 15) + (h << 8) + (l31 << 3);
    const int obase = l31 * 2048;
    const int oxor = (l31 & 7) << 4;
    bfx8 wfv[4], ofv[2];
#pragma unroll
    for (int pf = 0; pf < 4; ++pf) wfv[pf] = *(const bfx8*)(wp + ((kh * 32 + pf) << 9));
#pragma unroll
    for (int pf = 0; pf < 2; ++pf) {
      const int sl = 2 * (kh * 32 + pf) + h;
      ofv[pf] = *(const bfx8*)(o_sh + obase + ((sl << 4) ^ oxor));
    }
    f32x16 accB = {};
#pragma unroll
    for (int k = 0; k < 32; ++k) {
      __builtin_amdgcn_s_setprio(1);
      accB = __builtin_amdgcn_mfma_f32_32x32x16_bf16(wfv[k & 3], ofv[k & 1], accB, 0, 0, 0);
      __builtin_amdgcn_s_setprio(0);
      if (k + 4 < 32) wfv[k & 3] = *(const bfx8*)(wp + ((kh * 32 + k + 4) << 9));
      if (k + 2 < 32) {
        const int sl = 2 * (kh * 32 + k + 2) + h;
        ofv[k & 1] = *(const bfx8*)(o_sh + obase + ((sl << 4) ^ oxor));
      }
    }
    __syncthreads();   // all O reads done; o_sh front reusable for partials

    // partial fx4 at [kh][zt][s*32 + p], s = g2*2 + h
#pragma unroll
    for (int g2 = 0; g2 < 4; ++g2) {
      fx4 v = { accB[4 * g2], accB[4 * g2 + 1], accB[4 * g2 + 2], accB[4 * g2 + 3] };
      const int s = g2 * 2 + h;
      *(fx4*)(o_sh + kh * 16384 + zt * 4096 + ((s * 32 + l31) << 4)) = v;
    }
  }
  __syncthreads();

  // ---- coop epilogue: sum K-halves + bias, non-temporal stores (keep L2 for w2/a/b)
#pragma unroll
  for (int k = 0; k < 2; ++k) {
    const int v = tid + k * 512;
    const int zt2 = v >> 8, s2 = (v >> 5) & 7, pp = v & 31;
    const int off = zt2 * 4096 + ((s2 * 32 + pp) << 4);
    fx4 r = *(fx4*)(o_sh + off) + *(fx4*)(o_sh + 16384 + off);
    const int z0 = zt2 * 32 + s2 * 4;
    r += *(const fx4*)(bout + z0);
    const int i = i0 + (pp >> 2), j = j0 + (pp & 3);
    __builtin_nontemporal_store(r, (fx4*)(out + (i * SDIM + j) * CZ + z0));
  }
}

extern "C" void kernel_launch(void* const* d_in, const int* in_sizes, int n_in,
                              void* d_out, int out_size, void* d_ws, size_t ws_size,
                              hipStream_t stream) {
  const float* m_si  = (const float*)d_in[0];
  const float* gamma = (const float*)d_in[1];
  const float* beta  = (const float*)d_in[2];
  const float* Wab   = (const float*)d_in[3];
  const float* Wout  = (const float*)d_in[4];
  const float* bout  = (const float*)d_in[5];
  float* out = (float*)d_out;

  char* ws = (char*)d_ws;
  unsigned short* a_t = (unsigned short*)ws;                    // 4 MB
  unsigned short* b_t = (unsigned short*)(ws + (4u << 20));     // 4 MB
  unsigned short* w2T = (unsigned short*)(ws + (8u << 20));     // 256 KB

  opm_prep<<<dim3(2 * SDIM + 8), dim3(256), 0, stream>>>(m_si, gamma, beta, Wab, Wout, a_t, b_t, w2T);
  opm_main<<<dim3(2048), dim3(512), 0, stream>>>(a_t, b_t, w2T, bout, out);
}

// Round 7
// 81.415 us; speedup vs baseline: 2.0112x; 1.0545x over previous
//
#include <hip/hip_runtime.h>

#define SDIM 256
#define NSEQ 256
#define CDIM 32
#define CZ 128
#define IB 8
#define JB 4

typedef __bf16 bfx8 __attribute__((ext_vector_type(8)));
typedef float fx4 __attribute__((ext_vector_type(4)));
typedef float f32x16 __attribute__((ext_vector_type(16)));
typedef unsigned int u32x4 __attribute__((ext_vector_type(4)));

__device__ __forceinline__ unsigned short f2bf(float f) {
  unsigned int u = __float_as_uint(f);
  u += 0x7fffu + ((u >> 16) & 1u);
  return (unsigned short)(u >> 16);
}

__device__ __forceinline__ unsigned int cvtpk(float lo, float hi) {
  unsigned int r;
  asm("v_cvt_pk_bf16_f32 %0, %1, %2" : "=v"(r) : "v"(lo), "v"(hi));
  return r;
}

__device__ __forceinline__ void gload16(const void* g, void* l) {
  __builtin_amdgcn_global_load_lds((const __attribute__((address_space(1))) unsigned int*)g,
                                   (__attribute__((address_space(3))) unsigned int*)l,
                                   16, 0, 0);
}

// sigma(d,c): k' = e(c0,c1,c3) + 8*sl, sl = d + 32*c2 + 64*c4  (c2 = MFMA h-bit)

// ---------------- prep ----------------
// blocks [0,512): LN + half of ab-projection (dph: 0->a, 1->b), per s
// blocks [512,544): W_out -> w2T repack (4 z-rows each)
__global__ __launch_bounds__(256) void opm_prep(
    const float* __restrict__ m_si, const float* __restrict__ gamma, const float* __restrict__ beta,
    const float* __restrict__ Wab, const float* __restrict__ Wout,
    unsigned short* __restrict__ a_t, unsigned short* __restrict__ b_t,
    unsigned short* __restrict__ w2T)
{
  __shared__ __align__(16) char shbuf[41216];
  const int b = blockIdx.x;
  const int t = threadIdx.x;
  if (b < 2 * SDIM) {
    float* xin = (float*)shbuf;                      // f32 [256][36] (padded)
    unsigned short* xt = (unsigned short*)shbuf;     // later: bf16 [32][256]
    fx4* wab4 = (fx4*)(shbuf + 36864);               // [32][8]
    float* gbuf = (float*)(shbuf + 36864 + 4096);    // [64]
    const int s = b >> 1, dph = b & 1;

    const float* msrc = m_si + s * 8192;
#pragma unroll
    for (int k = 0; k < 8; ++k) {
      const int q = t + k * 256;
      ((fx4*)xin)[(q >> 3) * 9 + (q & 7)] = ((const fx4*)msrc)[q];
    }
    wab4[t & 255] = ((const fx4*)(Wab + dph * 1024))[t & 255];
    if (t < 32) { gbuf[t] = gamma[t]; gbuf[32 + t] = beta[t]; }
    __syncthreads();

    float x[CDIM];
#pragma unroll
    for (int c = 0; c < CDIM; ++c) x[c] = xin[t * 36 + c];
    __syncthreads();   // xin reads done; shbuf reusable as xt

    float mu = 0.f;
#pragma unroll
    for (int c = 0; c < CDIM; ++c) mu += x[c];
    mu *= (1.f / CDIM);
    float var = 0.f;
#pragma unroll
    for (int c = 0; c < CDIM; ++c) { float d = x[c] - mu; var += d * d; }
    var *= (1.f / CDIM);
    const float inv = rsqrtf(var + 1e-5f);
    fx4 xv[8];
#pragma unroll
    for (int cq = 0; cq < 8; ++cq) {
      fx4 v;
#pragma unroll
      for (int j = 0; j < 4; ++j) {
        const int c = cq * 4 + j;
        v[j] = (x[c] - mu) * inv * gbuf[c] + gbuf[32 + c];
      }
      xv[cq] = v;
    }

    for (int dp = 0; dp < 32; ++dp) {
      fx4 a = xv[0] * wab4[dp * 8];
#pragma unroll
      for (int cq = 1; cq < 8; ++cq) a += xv[cq] * wab4[dp * 8 + cq];
      xt[dp * 256 + t] = f2bf(a[0] + a[1] + a[2] + a[3]);
    }
    __syncthreads();

    unsigned short* outb = dph ? b_t : a_t;
#pragma unroll
    for (int k = 0; k < 4; ++k) {
      const int q = t + k * 256;          // 16B chunks
      const int row = q >> 5, cc = q & 31;
      *(u32x4*)(outb + (s * 32 + row) * 256 + cc * 8) = *(const u32x4*)(shbuf + row * 512 + cc * 16);
    }
  } else {
    // repack: 32 blocks, 4 z-rows each: coalesced load -> LDS bf16 [4][1024] -> gather-write
    unsigned short* lin = (unsigned short*)shbuf;    // 8 KB
    const int blk = b - 2 * SDIM;                    // 0..31
    const float* wsrc = Wout + blk * 4096;
#pragma unroll
    for (int jj = 0; jj < 4; ++jj) {
      const int q = t + jj * 256;                    // fx4 id
      const fx4 v = ((const fx4*)wsrc)[q];
      unsigned short* dst = lin + q * 4;
      dst[0] = f2bf(v[0]); dst[1] = f2bf(v[1]); dst[2] = f2bf(v[2]); dst[3] = f2bf(v[3]);
    }
    __syncthreads();
    const int z0 = blk * 4;
#pragma unroll
    for (int w = 0; w < 2; ++w) {
      const int id = t + w * 256;        // [0,512)
      const int lz = id & 3;
      const int hh = (id >> 2) & 1;
      const int ks = id >> 3;            // 0..63
      const int z = z0 + lz;
      unsigned short vals[8];
#pragma unroll
      for (int e = 0; e < 8; ++e) {
        const int kp = ks * 16 + hh * 8 + e;
        const int c = (kp & 3) | (((kp >> 8) & 1) << 2) | (((kp >> 2) & 1) << 3) | (((kp >> 9) & 1) << 4);
        const int d = (kp >> 3) & 31;
        vals[e] = lin[lz * 1024 + c * CDIM + d];
      }
      const int dest = ((z >> 5) << 15) + (ks << 9) + (hh << 8) + ((z & 31) << 3);
      *(u32x4*)(w2T + dest) = *(const u32x4*)vals;
    }
  }
}

// ---------------- main: 8x4 (i,j) tiles = 32 pairs/block, 32x32x16 MFMA ----------------
__global__ __launch_bounds__(512, 4) void opm_main(
    const unsigned short* __restrict__ a_t, const unsigned short* __restrict__ b_t,
    const unsigned short* __restrict__ w2T, const float* __restrict__ bout,
    float* __restrict__ out)
{
  // O [0,64K) overlays staging: A0 [16K,32K) A1 [32K,48K) B0 [48K,56K) B1 [56K,64K)
  __shared__ __align__(16) char smem[65536];
  char* o_sh = smem;

  const int tid = threadIdx.x;
  const int lane = tid & 63;
  const int wid = tid >> 6;           // 0..7
  const int l31 = lane & 31;
  const int h = lane >> 5;

  // 2-D XCD blocking: each XCD owns 16i x 16j chunk (3.25 MB working set < 4 MB L2)
  const int bxr = blockIdx.x;
  const int xc = bxr & 7;
  const int q8 = bxr >> 3;            // 0..255
  const int it = q8 >> 4;             // 0..15
  const int jt = q8 & 15;             // 0..15
  const int i0 = ((xc & 1) * 16 + it) * IB;
  const int j0 = ((xc >> 1) * 16 + jt) * JB;

  const int wm = wid >> 1;            // 0..3: M 64-row group
  const int wn = wid & 1;             // 0..1: N 64-row group
  const int wbase = wid * 1024;       // wave-uniform LDS staging offset

  f32x16 acc00 = {}, acc01 = {}, acc10 = {}, acc11 = {};

  // chunk q (16B) at LDS offset q*16 holds global n-group gs = (q&3) ^ ((q>>3)&3)
  auto STAGE = [&](int buf, int nc) {
    const int nbase = nc * 32;
    char* A = smem + 16384 + buf * 16384;
    char* B = smem + 49152 + buf * 8192;
#pragma unroll
    for (int pass = 0; pass < 2; ++pass) {
      const int q = pass * 512 + tid;
      const int row = q >> 2;
      const int gs = (q & 3) ^ ((q >> 3) & 3);
      const unsigned short* src = a_t + ((i0 + (row >> 5)) * 32 + (row & 31)) * 256 + nbase + gs * 8;
      gload16(src, A + pass * 8192 + wbase);
    }
    {
      const int q = tid;
      const int row = q >> 2;
      const int gs = (q & 3) ^ ((q >> 3) & 3);
      const unsigned short* src = b_t + ((j0 + (row >> 5)) * 32 + (row & 31)) * 256 + nbase + gs * 8;
      gload16(src, B + wbase);
    }
  };

  auto COMPUTE = [&](int buf) {
    char* A = smem + 16384 + buf * 16384;
    char* B = smem + 49152 + buf * 8192;
#pragma unroll
    for (int ks = 0; ks < 2; ++ks) {
      const int s = ks * 2 + h;
      bfx8 af0, af1, bf0, bf1;
      { const int r = wm * 64 + l31;      af0 = *(const bfx8*)(A + r * 64 + (((s ^ (r >> 1)) & 3) << 4)); }
      { const int r = wm * 64 + 32 + l31; af1 = *(const bfx8*)(A + r * 64 + (((s ^ (r >> 1)) & 3) << 4)); }
      { const int r = wn * 64 + l31;      bf0 = *(const bfx8*)(B + r * 64 + (((s ^ (r >> 1)) & 3) << 4)); }
      { const int r = wn * 64 + 32 + l31; bf1 = *(const bfx8*)(B + r * 64 + (((s ^ (r >> 1)) & 3) << 4)); }
      __builtin_amdgcn_s_setprio(1);
      acc00 = __builtin_amdgcn_mfma_f32_32x32x16_bf16(af0, bf0, acc00, 0, 0, 0);
      acc01 = __builtin_amdgcn_mfma_f32_32x32x16_bf16(af0, bf1, acc01, 0, 0, 0);
      acc10 = __builtin_amdgcn_mfma_f32_32x32x16_bf16(af1, bf0, acc10, 0, 0, 0);
      acc11 = __builtin_amdgcn_mfma_f32_32x32x16_bf16(af1, bf1, acc11, 0, 0, 0);
      __builtin_amdgcn_s_setprio(0);
    }
  };

  STAGE(0, 0);
#pragma unroll 2
  for (int t = 0; t < 8; ++t) {
    if (t < 7) {
      STAGE((t + 1) & 1, t + 1);
      asm volatile("s_waitcnt vmcnt(3)" ::: "memory");
    } else {
      asm volatile("s_waitcnt vmcnt(0)" ::: "memory");
    }
    __builtin_amdgcn_s_barrier();
    asm volatile("" ::: "memory");
    COMPUTE(t & 1);
    asm volatile("s_waitcnt lgkmcnt(0)" ::: "memory");
    __builtin_amdgcn_s_barrier();
  }

  // ---- O -> LDS: pair p at [p*2048 + ((d + 32*c2 + 64*c4) ^ (p&7))*16]
  {
    const f32x16 av[4] = { acc00 * 0.00390625f, acc01 * 0.00390625f,
                           acc10 * 0.00390625f, acc11 * 0.00390625f };
#pragma unroll
    for (int mi = 0; mi < 2; ++mi) {
#pragma unroll
      for (int ni = 0; ni < 2; ++ni) {
        const f32x16 a = av[mi * 2 + ni];
        const int p = (wm * 2 + mi) * 4 + (wn * 2 + ni);
#pragma unroll
        for (int c4 = 0; c4 < 2; ++c4) {
          const int sl = l31 + 32 * h + 64 * c4;
          u32x4 v;
          v[0] = cvtpk(a[8 * c4 + 0], a[8 * c4 + 1]);
          v[1] = cvtpk(a[8 * c4 + 2], a[8 * c4 + 3]);
          v[2] = cvtpk(a[8 * c4 + 4], a[8 * c4 + 5]);
          v[3] = cvtpk(a[8 * c4 + 6], a[8 * c4 + 7]);
          *(u32x4*)(o_sh + p * 2048 + ((sl ^ (p & 7)) << 4)) = v;
        }
      }
    }
  }
  __syncthreads();

  // ---- phase B: waves (ztp 0-1 = z'-tile pair, kh 0-3 = K-quarter); of shared by 2 MFMAs
  {
    const int ztp = wid & 1;
    const int kh = wid >> 1;
    const unsigned short* wpa = w2T + ((ztp * 2 + 0) << 15) + (h << 8) + (l31 << 3);
    const unsigned short* wpb = w2T + ((ztp * 2 + 1) << 15) + (h << 8) + (l31 << 3);
    const int obase = l31 * 2048;
    const int oxor = l31 & 7;
    const int ks0 = kh * 16;

    bfx8 wa[4], wb[4];
#pragma unroll
    for (int q = 0; q < 4; ++q) {
      wa[q] = *(const bfx8*)(wpa + ((ks0 + q) << 9));
      wb[q] = *(const bfx8*)(wpb + ((ks0 + q) << 9));
    }
    bfx8 oc = *(const bfx8*)(o_sh + obase + ((((ks0 << 1) + h) ^ oxor) << 4));
    bfx8 on = *(const bfx8*)(o_sh + obase + (((((ks0 + 1) << 1) + h) ^ oxor) << 4));

    f32x16 za = {}, zb = {};
#pragma unroll
    for (int st = 0; st < 16; ++st) {
      const int q = st & 3;
      __builtin_amdgcn_s_setprio(1);
      za = __builtin_amdgcn_mfma_f32_32x32x16_bf16(wa[q], oc, za, 0, 0, 0);
      zb = __builtin_amdgcn_mfma_f32_32x32x16_bf16(wb[q], oc, zb, 0, 0, 0);
      __builtin_amdgcn_s_setprio(0);
      oc = on;
      if (st < 14) on = *(const bfx8*)(o_sh + obase + (((((ks0 + st + 2) << 1) + h) ^ oxor) << 4));
      if (st < 12) {
        wa[q] = *(const bfx8*)(wpa + ((ks0 + st + 4) << 9));
        wb[q] = *(const bfx8*)(wpb + ((ks0 + st + 4) << 9));
      }
    }
    __syncthreads();   // all O reads done; o_sh reusable for partials

    // pairwise kh reduction: (0<-1), (2<-3), then (0<-2); partials fx4 [slot][zs][g2*2+h][p]
    const int slot = (kh >> 1) * 2 + ztp;
    auto PWRITE = [&](char* base) {
#pragma unroll
      for (int zs = 0; zs < 2; ++zs) {
        const f32x16& A = zs ? zb : za;
#pragma unroll
        for (int g2 = 0; g2 < 4; ++g2) {
          fx4 v = { A[4 * g2], A[4 * g2 + 1], A[4 * g2 + 2], A[4 * g2 + 3] };
          *(fx4*)(base + zs * 4096 + (((g2 * 2 + h) * 32 + l31) << 4)) = v;
        }
      }
    };
    auto PADD = [&](const char* base) {
#pragma unroll
      for (int zs = 0; zs < 2; ++zs) {
        f32x16& A = zs ? zb : za;
#pragma unroll
        for (int g2 = 0; g2 < 4; ++g2) {
          const fx4 v = *(const fx4*)(base + zs * 4096 + (((g2 * 2 + h) * 32 + l31) << 4));
          A[4 * g2 + 0] += v[0]; A[4 * g2 + 1] += v[1];
          A[4 * g2 + 2] += v[2]; A[4 * g2 + 3] += v[3];
        }
      }
    };
    if (kh & 1) PWRITE(o_sh + slot * 8192);
    __syncthreads();
    if (!(kh & 1)) {
      PADD(o_sh + slot * 8192);
      if (kh == 2) PWRITE(o_sh + 32768 + ztp * 8192);
    }
    __syncthreads();
    if (kh == 0) {
      PADD(o_sh + 32768 + ztp * 8192);
      const int i = i0 + (l31 >> 2), j = j0 + (l31 & 3);
      float* op = out + (i * SDIM + j) * CZ + ztp * 64;
      const float* bp = bout + ztp * 64;
#pragma unroll
      for (int zs = 0; zs < 2; ++zs) {
        const f32x16& A = zs ? zb : za;
#pragma unroll
        for (int g2 = 0; g2 < 4; ++g2) {
          const int zl = zs * 32 + g2 * 8 + h * 4;
          fx4 v = { A[4 * g2], A[4 * g2 + 1], A[4 * g2 + 2], A[4 * g2 + 3] };
          v += *(const fx4*)(bp + zl);
          *(fx4*)(op + zl) = v;
        }
      }
    }
  }
}

extern "C" void kernel_launch(void* const* d_in, const int* in_sizes, int n_in,
                              void* d_out, int out_size, void* d_ws, size_t ws_size,
                              hipStream_t stream) {
  const float* m_si  = (const float*)d_in[0];
  const float* gamma = (const float*)d_in[1];
  const float* beta  = (const float*)d_in[2];
  const float* Wab   = (const float*)d_in[3];
  const float* Wout  = (const float*)d_in[4];
  const float* bout  = (const float*)d_in[5];
  float* out = (float*)d_out;

  char* ws = (char*)d_ws;
  unsigned short* a_t = (unsigned short*)ws;                    // 4 MB
  unsigned short* b_t = (unsigned short*)(ws + (4u << 20));     // 4 MB
  unsigned short* w2T = (unsigned short*)(ws + (8u << 20));     // 256 KB

  opm_prep<<<dim3(2 * SDIM + 32), dim3(256), 0, stream>>>(m_si, gamma, beta, Wab, Wout, a_t, b_t, w2T);
  opm_main<<<dim3(2048), dim3(512), 0, stream>>>(a_t, b_t, w2T, bout, out);
}